// Round 9
// baseline (128.828 us; speedup 1.0000x reference)
//
#include <hip/hip_runtime.h>

// CTC loss forward, f64 prob-domain with power-of-2 rescaling.
// v10: v5 skeleton (fwd/bwd separate blocks, 4 waves x 4 states, ghost-zone
// halo, chunked rescale) + ASM-PINNED gather pipeline + folded combine.
// v9 post-mortem: VGPR stuck at 68 across slot depths 3/6 -> the compiler
// collapses rotating slots and re-sinks gathers toward uses (v7 sink, v8
// spill, v9 collapse). v10 pins with the only un-undoable tool:
//  (a) each pair's 6 column reads = ONE volatile asm block of ds_read_b32
//      (early-clobber outs -> values stay live; volatile -> cannot sink);
//  (b) consumption guarded by explicit "s_waitcnt lgkmcnt(12)" +
//      sched_barrier(0) (newer reads at consume = exactly 2 pairs x 6);
//  (c) syncex begins with lgkmcnt(0) drain (slot-copy hazard + compiler
//      LDS ops isolated there);
//  (d) combine folded into fb kernel via last-finisher device-scope atomic
//      (v8-verified pattern) -- one launch, no combine dispatch.
// f64 op order per state IDENTICAL to v5; bwd cc via f32 DPP of ca
// (v9-verified bit-identical) -> absmax must stay 0.0.
// ws layout per b (doubles, stride 1028): [0..512] alphaF, [513] toteF,
// [514..1026] betaB, [1027] toteB; int flags at double-offset 64*1028.

#define Bc 64
#define Tc 1024
#define Cc 128
#define Lc 256
#define Sc 513
#define BLANKc 127
#define CHUNK 32
#define NW 4
#define PADS 64
#define WSSTRIDE 1028
#define FLAGS_OFF (Bc * WSSTRIDE)

constexpr float EPSF = 1e-7f;

#define LDS3(p) ((const __attribute__((address_space(3))) float*)(p))

#define DPPMAXI(x, ctrl) max(x, __builtin_amdgcn_update_dpp( \
    0, x, ctrl, 0xf, 0xf, true))

// wait until only the 2 newest pair-gathers (12 reads) are outstanding;
// sched_barrier stops VALU consumers hoisting above the opaque waitcnt.
#define WAITSLOT() do {                                      \
    asm volatile("s_waitcnt lgkmcnt(12)");                   \
    __builtin_amdgcn_sched_barrier(0);                       \
} while (0)

#define DRAINLGKM() do {                                     \
    asm volatile("s_waitcnt lgkmcnt(0)" ::: "memory");       \
    __builtin_amdgcn_sched_barrier(0);                       \
} while (0)

__device__ __forceinline__ double dpp_wave_shr1_f64(double x) {
    // lane l <- lane l-1; lane 0 <- 0 (bound_ctrl)
    union { double d; int i[2]; } u, r;
    u.d = x;
    r.i[0] = __builtin_amdgcn_update_dpp(0, u.i[0], 0x138, 0xf, 0xf, true);
    r.i[1] = __builtin_amdgcn_update_dpp(0, u.i[1], 0x138, 0xf, 0xf, true);
    return r.d;
}
__device__ __forceinline__ double dpp_wave_shl1_f64(double x) {
    // lane l <- lane l+1; lane 63 <- 0 (bound_ctrl)
    union { double d; int i[2]; } u, r;
    u.d = x;
    r.i[0] = __builtin_amdgcn_update_dpp(0, u.i[0], 0x130, 0xf, 0xf, true);
    r.i[1] = __builtin_amdgcn_update_dpp(0, u.i[1], 0x130, 0xf, 0xf, true);
    return r.d;
}
__device__ __forceinline__ float dpp_wave_shl1_f32(float x) {
    union { float f; int i; } u, r;
    u.f = x;
    r.i = __builtin_amdgcn_update_dpp(0, u.i, 0x130, 0xf, 0xf, true);
    return r.f;
}

__global__ __launch_bounds__(256, 1) void ctc_fb_kernel(
    const int* __restrict__ y_true,        // [B, L]
    const float* __restrict__ y_pred,      // [B, T, C]
    const int* __restrict__ label_length,  // [B, 1]
    double* __restrict__ ws,
    float* __restrict__ out)               // [B, 1]
{
    const int bb = blockIdx.x;
    const int b = bb >> 1;
    const bool isF = !(bb & 1);
    const int tid = (int)threadIdx.x;
    const int wl = tid >> 6;               // wave 0..3
    const int lane = tid & 63;

    __shared__ float bufs[3][CHUNK * Cc];  // 3 x 16 KB staged y_pred rows
    __shared__ double ash[Sc];             // owned-alpha/beta exchange
    __shared__ int em[NW];                 // per-wave masked exponent max
    __shared__ int amlast;

    const int lab_len = label_length[b];
    const float* yp = y_pred + (size_t)b * Tc * Cc;
    const int* lab = y_true + b * Lc;
    double* wsb = ws + (size_t)b * WSSTRIDE;

    // ---- region geometry (starts EVEN). fwd pads BELOW owned, bwd ABOVE.
    const int start = isF ? ((wl == 0) ? 0 : (128 * wl - PADS)) : (128 * wl);
    const int own_s = 128 * wl;
    const int own_e = (wl == NW - 1) ? Sc : (128 * (wl + 1));
    const int s0 = start + 4 * lane;       // even; lane holds s0..s0+3

    // ---- per-lane static metadata ----
    const int li0 = s0 >> 1;               // label idx of state s0+1
    const int li0c = min(li0, Lc - 1);
    const int li1c = min(li0 + 1, Lc - 1);
    const int li2c = min(li0 + 2, Lc - 1);
    const int ca = lab[li0c], cb = lab[li1c], cc = lab[li2c];
    const double sm_a = (li0 > 0 && ca != BLANKc && ca != lab[li0c - 1]) ? 1.0 : 0.0;
    const double sm_b = (cb != BLANKc && cb != ca) ? 1.0 : 0.0;
    const double sm_c = (cc != BLANKc && cc != cb) ? 1.0 : 0.0;

    const int S2 = 2 * lab_len + 1;
    const bool ow0 = (s0     >= own_s) && (s0     < own_e);
    const bool ow1 = (s0 + 1 >= own_s) && (s0 + 1 < own_e);
    const bool ow2 = (s0 + 2 >= own_s) && (s0 + 2 < own_e);
    const bool ow3 = (s0 + 3 >= own_s) && (s0 + 3 < own_e);
    const int om0 = (ow0 && s0     < S2) ? -1 : 0;
    const int om1 = (ow1 && s0 + 1 < S2) ? -1 : 0;
    const int om2 = (ow2 && s0 + 2 < S2) ? -1 : 0;
    const int om3 = (ow3 && s0 + 3 < S2) ? -1 : 0;

    // ---- staging: each wave DMAs its quarter (4 KB) of a 16 KB chunk ----
    auto stage = [&](int c, float* dst) {
        const float* g = yp + (size_t)c * (CHUNK * Cc) + lane * 4;
        #pragma unroll
        for (int q = 0; q < 4; ++q) {
            const int i = wl * 4 + q;
            __builtin_amdgcn_global_load_lds(
                (const __attribute__((address_space(1))) void*)(g + i * 256),
                (__attribute__((address_space(3))) void*)(dst + i * 256),
                16, 0, 0);
        }
    };

    // ---- 4 rotating pair slots, pair P in sl[P&3]; gathered 3 ahead ----
    // [0]=blank_e [1]=blank_o [2]=ca_e [3]=ca_o [4]=cb_e [5]=cb_o
    float sl[4][6];

    // volatile asm: 6 reads issue HERE and cannot sink; outputs stay live.
    auto gpair = [&](const float* rowp, float* s) {
        asm volatile(
            "ds_read_b32 %0, %6\n\t"
            "ds_read_b32 %1, %6 offset:512\n\t"
            "ds_read_b32 %2, %7\n\t"
            "ds_read_b32 %3, %7 offset:512\n\t"
            "ds_read_b32 %4, %8\n\t"
            "ds_read_b32 %5, %8 offset:512\n\t"
            : "=&v"(s[0]), "=&v"(s[1]), "=&v"(s[2]),
              "=&v"(s[3]), "=&v"(s[4]), "=&v"(s[5])
            : "v"(LDS3(rowp + BLANKc)), "v"(LDS3(rowp + ca)),
              "v"(LDS3(rowp + cb)));
    };

    if (isF) {
        // =================== FORWARD: rows 0 .. 511 ===================
        double a0 = 0, a1 = 0, a2 = 0, a3 = 0, n3 = 0;
        int tote = 0;
        double Eb, Ea, Ec, Ob, Oa, Oc;

        auto expandE = [&](const float* s) {
            Eb = (double)(s[0] + EPSF); Ea = (double)(s[2] + EPSF);
            Ec = (double)(s[4] + EPSF);
        };
        auto expandO = [&](const float* s) {
            Ob = (double)(s[1] + EPSF); Oa = (double)(s[3] + EPSF);
            Oc = (double)(s[5] + EPSF);
        };
        auto stepE = [&]() {
            const double t3 = __fma_rn(sm_b, a1, a3 + a2);
            const double t2 = a2 + a1;
            const double t1 = __fma_rn(sm_a, n3, a1 + a0);
            const double t0 = a0 + n3;
            a3 = t3 * Ec;
            n3 = dpp_wave_shr1_f64(a3);
            a2 = t2 * Eb; a1 = t1 * Ea; a0 = t0 * Eb;
        };
        auto stepO = [&]() {
            const double t3 = __fma_rn(sm_b, a1, a3 + a2);
            const double t2 = a2 + a1;
            const double t1 = __fma_rn(sm_a, n3, a1 + a0);
            const double t0 = a0 + n3;
            a3 = t3 * Oc;
            n3 = dpp_wave_shr1_f64(a3);
            a2 = t2 * Ob; a1 = t1 * Oa; a0 = t0 * Ob;
        };
        auto syncex = [&](int sk) {
            DRAINLGKM();                   // pre-gathered next-chunk slots safe
            int e =        om0 & (__double2hiint(a0) >> 20);
            e = max(e, om1 & (__double2hiint(a1) >> 20));
            e = max(e, om2 & (__double2hiint(a2) >> 20));
            e = max(e, om3 & (__double2hiint(a3) >> 20));
            e = DPPMAXI(e, 0x111); e = DPPMAXI(e, 0x112);
            e = DPPMAXI(e, 0x114); e = DPPMAXI(e, 0x118);
            e = DPPMAXI(e, 0x142); e = DPPMAXI(e, 0x143);
            if (lane == 63) em[wl] = e;
            if (ow0) ash[s0]     = a0;
            if (ow1) ash[s0 + 1] = a1;
            if (ow2) ash[s0 + 2] = a2;
            if (ow3) ash[s0 + 3] = a3;
            __syncthreads();               // barrier 1
            const int eg = max(max(em[0], em[1]), max(em[2], em[3]));
            const int sexp = min(max(2046 - eg, 1), 2045);
            const double sc = __hiloint2double(sexp << 20, 0);
            tote += 1023 - sexp;
            if (wl > 0 && lane < (PADS / 4)) {   // refresh pad from below-owner
                a0 = ash[s0];     a1 = ash[s0 + 1];
                a2 = ash[s0 + 2]; a3 = ash[s0 + 3];
            }
            a0 *= sc; a1 *= sc; a2 *= sc; a3 *= sc;
            n3 = dpp_wave_shr1_f64(a3);
            __syncthreads();               // barrier 2
            if (sk <= 15) stage(sk, bufs[sk % 3]);  // DMA after barrier
        };

        // ---- prologue ----
        stage(0, bufs[0]); stage(1, bufs[1]); stage(2, bufs[2]);
        __syncthreads();

        if (wl == 0 && lane == 0) {
            a0 = (double)(bufs[0][BLANKc] + EPSF);               // s=0
            if (lab_len > 0) a1 = (double)(bufs[0][ca] + EPSF);  // s=1
        }
        gpair(bufs[0] + 2 * Cc, sl[1]);
        gpair(bufs[0] + 4 * Cc, sl[2]);
        gpair(bufs[0] + 6 * Cc, sl[3]);
        {
            const float* r1 = bufs[0] + 1 * Cc;
            Ob = (double)(r1[BLANKc] + EPSF);
            Oa = (double)(r1[ca] + EPSF);
            Oc = (double)(r1[cb] + EPSF);
        }
        WAITSLOT();                        // pair 1 landed (pairs 2,3 newer)
        expandE(sl[1]);                    // row 2

        stepO();                           // lone step t=1
        expandO(sl[1]);                    // row 3

        // chunk 0: pairs 1..15 (rows 2..31)
        {
            const float* rb  = bufs[0];
            const float* rbn = bufs[1];
            #pragma unroll
            for (int qi = 1; qi < 16; ++qi) {
                const int rr = 2 * qi;
                const float* nxt = (rr + 6 < CHUNK) ? (rb + (rr + 6) * Cc)
                                                    : (rbn + (rr + 6 - CHUNK) * Cc);
                gpair(nxt, sl[(qi + 3) & 3]);
                stepE();
                WAITSLOT();
                expandE(sl[(qi + 1) & 3]);
                stepO();
                expandO(sl[(qi + 1) & 3]);
            }
        }
        // chunks 1..15 (rows 32..511)
        for (int k = 1; k < 16; ++k) {
            syncex(k + 2);
            const float* rb  = bufs[k % 3];
            const float* rbn = bufs[(k + 1) % 3];    // k=15: dead reads, safe
            #pragma unroll
            for (int qi = 0; qi < 16; ++qi) {
                const int rr = 2 * qi;
                const float* nxt = (rr + 6 < CHUNK) ? (rb + (rr + 6) * Cc)
                                                    : (rbn + (rr + 6 - CHUNK) * Cc);
                gpair(nxt, sl[(qi + 3) & 3]);
                stepE();
                WAITSLOT();
                expandE(sl[(qi + 1) & 3]);
                stepO();
                expandO(sl[(qi + 1) & 3]);
            }
        }
        DRAINLGKM();
        // publish alpha_511 (pre-rescale) + toteF
        if (ow0) wsb[s0]     = a0;
        if (ow1) wsb[s0 + 1] = a1;
        if (ow2) wsb[s0 + 2] = a2;
        if (ow3) wsb[s0 + 3] = a3;
        if (tid == 0) wsb[513] = (double)tote;
    } else {
        // =================== BACKWARD: rows 1023 .. 512 ===================
        double b0 = 0, b1 = 0, b2 = 0, b3 = 0, n0 = 0, n1 = 0;
        int tote = 0;
        double Eb, Ea, Ec, Ed, Ob, Oa, Oc, Od;

        auto expandEB = [&](const float* s) {
            Eb = (double)(s[0] + EPSF); Ea = (double)(s[2] + EPSF);
            Ec = (double)(s[4] + EPSF);
            Ed = (double)(dpp_wave_shl1_f32(s[2]) + EPSF);   // cc = nbr ca
        };
        auto expandOB = [&](const float* s) {
            Ob = (double)(s[1] + EPSF); Oa = (double)(s[3] + EPSF);
            Oc = (double)(s[5] + EPSF);
            Od = (double)(dpp_wave_shl1_f32(s[3]) + EPSF);
        };
        auto stepBE = [&]() {
            const double x1 = Ea * b1, x2 = Eb * b2, x3 = Ec * b3, z = Ed * n1;
            const double r0 = __fma_rn(Eb, b0, x1);
            const double r1 = __fma_rn(sm_b, x3, x1 + x2);
            const double r2 = x2 + x3;
            const double r3 = __fma_rn(sm_c, z, __fma_rn(Eb, n0, x3));
            b0 = r0; b1 = r1; b2 = r2; b3 = r3;
            n0 = dpp_wave_shl1_f64(b0);
            n1 = dpp_wave_shl1_f64(b1);
        };
        auto stepBO = [&]() {
            const double x1 = Oa * b1, x2 = Ob * b2, x3 = Oc * b3, z = Od * n1;
            const double r0 = __fma_rn(Ob, b0, x1);
            const double r1 = __fma_rn(sm_b, x3, x1 + x2);
            const double r2 = x2 + x3;
            const double r3 = __fma_rn(sm_c, z, __fma_rn(Ob, n0, x3));
            b0 = r0; b1 = r1; b2 = r2; b3 = r3;
            n0 = dpp_wave_shl1_f64(b0);
            n1 = dpp_wave_shl1_f64(b1);
        };
        auto syncex = [&](int sk) {
            DRAINLGKM();
            int e =        om0 & (__double2hiint(b0) >> 20);
            e = max(e, om1 & (__double2hiint(b1) >> 20));
            e = max(e, om2 & (__double2hiint(b2) >> 20));
            e = max(e, om3 & (__double2hiint(b3) >> 20));
            e = DPPMAXI(e, 0x111); e = DPPMAXI(e, 0x112);
            e = DPPMAXI(e, 0x114); e = DPPMAXI(e, 0x118);
            e = DPPMAXI(e, 0x142); e = DPPMAXI(e, 0x143);
            if (lane == 63) em[wl] = e;
            if (ow0) ash[s0]     = b0;
            if (ow1) ash[s0 + 1] = b1;
            if (ow2) ash[s0 + 2] = b2;
            if (ow3) ash[s0 + 3] = b3;
            __syncthreads();               // barrier 1
            const int eg = max(max(em[0], em[1]), max(em[2], em[3]));
            const int sexp = min(max(2046 - eg, 1), 2045);
            const double sc = __hiloint2double(sexp << 20, 0);
            tote += 1023 - sexp;
            // refresh pad above from owner; zero beyond S space
            if (s0     >= own_e) b0 = (s0     < Sc) ? ash[s0]     : 0.0;
            if (s0 + 1 >= own_e) b1 = (s0 + 1 < Sc) ? ash[s0 + 1] : 0.0;
            if (s0 + 2 >= own_e) b2 = (s0 + 2 < Sc) ? ash[s0 + 2] : 0.0;
            if (s0 + 3 >= own_e) b3 = (s0 + 3 < Sc) ? ash[s0 + 3] : 0.0;
            b0 *= sc; b1 *= sc; b2 *= sc; b3 *= sc;
            n0 = dpp_wave_shl1_f64(b0);
            n1 = dpp_wave_shl1_f64(b1);
            __syncthreads();               // barrier 2
            if (sk >= 16) stage(sk, bufs[(31 - sk) % 3]);
        };

        // ---- prologue: chunks 31,30,29 -> bufs 0,1,2 ----
        stage(31, bufs[0]); stage(30, bufs[1]); stage(29, bufs[2]);
        __syncthreads();

        // init beta_{1023}: 1 at end states {2L, 2L-1}
        {
            const int e0 = 2 * lab_len;
            const int e1 = (lab_len > 0) ? (2 * lab_len - 1) : e0;
            b0 = (s0     == e0 || s0     == e1) ? 1.0 : 0.0;
            b1 = (s0 + 1 == e0 || s0 + 1 == e1) ? 1.0 : 0.0;
            b2 = (s0 + 2 == e0 || s0 + 2 == e1) ? 1.0 : 0.0;
            b3 = (s0 + 3 == e0 || s0 + 3 == e1) ? 1.0 : 0.0;
            n0 = dpp_wave_shl1_f64(b0);
            n1 = dpp_wave_shl1_f64(b1);
        }
        // prime pairs 15,14,13 -> slots 3,2,1
        gpair(bufs[0] + 30 * Cc, sl[3]);
        gpair(bufs[0] + 28 * Cc, sl[2]);
        gpair(bufs[0] + 26 * Cc, sl[1]);
        WAITSLOT();                        // pair 15 landed (14,13 newer)
        expandOB(sl[3]);                   // row 31 (abs t=1023)
        expandEB(sl[3]);                   // row 30

        // chunk 31: q = 15..0 (rows descend; odd step first per pair)
        {
            const float* rb  = bufs[0];
            const float* rbn = bufs[1];    // chunk 30
            #pragma unroll
            for (int j = 0; j < 16; ++j) {
                const int q = 15 - j;
                const int rr = 2 * q;
                const float* nxt = (rr - 6 >= 0) ? (rb + (rr - 6) * Cc)
                                                 : (rbn + (rr - 6 + CHUNK) * Cc);
                gpair(nxt, sl[(q + 1) & 3]);   // pair q-3
                stepBO();
                WAITSLOT();
                expandOB(sl[(q - 1) & 3]);
                stepBE();
                expandEB(sl[(q - 1) & 3]);
            }
        }
        // chunks 30..16
        for (int c = 30; c >= 16; --c) {
            syncex(c - 2);
            const float* rb  = bufs[(31 - c) % 3];
            const float* rbn = bufs[(32 - c) % 3];   // c=16: dead reads, safe
            #pragma unroll
            for (int j = 0; j < 16; ++j) {
                const int q = 15 - j;
                const int rr = 2 * q;
                const float* nxt = (rr - 6 >= 0) ? (rb + (rr - 6) * Cc)
                                                 : (rbn + (rr - 6 + CHUNK) * Cc);
                gpair(nxt, sl[(q + 1) & 3]);
                stepBO();
                WAITSLOT();
                expandOB(sl[(q - 1) & 3]);
                stepBE();
                expandEB(sl[(q - 1) & 3]);
            }
        }
        DRAINLGKM();
        // publish beta_511 (pre-rescale) + toteB
        if (ow0) wsb[514 + s0]     = b0;
        if (ow1) wsb[514 + s0 + 1] = b1;
        if (ow2) wsb[514 + s0 + 2] = b2;
        if (ow3) wsb[514 + s0 + 3] = b3;
        if (tid == 0) wsb[1027] = (double)tote;
    }

    // ---- folded combine: last finisher for batch b does dot + log ----
    __threadfence();                       // release our ws writes
    if (tid == 0) {
        int* flags = (int*)(ws + FLAGS_OFF);
        amlast = (atomicAdd(&flags[b], 1) == 1);
    }
    __syncthreads();
    if (amlast && tid < 64) {
        __threadfence();                   // acquire other block's writes
        const double* wf = ws + (size_t)b * WSSTRIDE;
        const double* wb = wf + 514;
        int eP = 0;                        // max biased-exponent product sum
        for (int s = tid; s < S2; s += 64) {
            const int ea = (__double2hiint(wf[s]) >> 20) & 0x7ff;
            const int eb2 = (__double2hiint(wb[s]) >> 20) & 0x7ff;
            if (ea && eb2) eP = max(eP, ea + eb2);
        }
        #pragma unroll
        for (int m = 1; m < 64; m <<= 1) eP = max(eP, __shfl_xor(eP, m));
        const int sh = 2046 - eP;
        int k1 = sh / 2;
        int k2 = sh - k1;
        k1 = min(max(k1, -1022), 1023);
        k2 = min(max(k2, -1022), 1023);
        const double scA = __hiloint2double((1023 + k1) << 20, 0);
        const double scB = __hiloint2double((1023 + k2) << 20, 0);
        double dot = 0.0;
        for (int s = tid; s < S2; s += 64)
            dot += (wf[s] * scA) * (wb[s] * scB);
        #pragma unroll
        for (int m = 1; m < 64; m <<= 1) dot += __shfl_xor(dot, m);
        if (tid == 0) {
            const double lt = wf[513] + wb[513] - (double)k1 - (double)k2;
            out[b] = (float)(-(log(dot) + lt * 0.6931471805599453));
        }
    }
}

extern "C" void kernel_launch(void* const* d_in, const int* in_sizes, int n_in,
                              void* d_out, int out_size, void* d_ws, size_t ws_size,
                              hipStream_t stream) {
    const int*   y_true       = (const int*)d_in[0];
    const float* y_pred       = (const float*)d_in[1];
    const int*   label_length = (const int*)d_in[3];
    float* out = (float*)d_out;
    double* ws = (double*)d_ws;

    hipMemsetAsync((char*)d_ws + FLAGS_OFF * sizeof(double), 0,
                   Bc * sizeof(int), stream);
    ctc_fb_kernel<<<2 * Bc, NW * 64, 0, stream>>>(y_true, y_pred,
                                                  label_length, ws, out);
}